// Round 22
// baseline (328.764 us; speedup 1.0000x reference)
//
#include <hip/hip_runtime.h>
#include <stdint.h>

typedef __bf16 bf16_t;
typedef __bf16 bf16x8 __attribute__((ext_vector_type(8)));
typedef __bf16 bf16x4 __attribute__((ext_vector_type(4)));
typedef float f32x4 __attribute__((ext_vector_type(4)));

#define DEV static __device__ __forceinline__

// problem constants
#define SB 2
#define SS 2048
#define SD 2048
#define SNQ 16
#define SNKV 8
#define SH 256
#define SWIN 1024
#define QKVP 8192   // fused projection output pitch (Q | K | V)

DEV void async_ld16(const void* g, void* lds) {
  __builtin_amdgcn_global_load_lds(
      (const __attribute__((address_space(1))) void*)g,
      (__attribute__((address_space(3))) void*)lds, 16, 0, 0);
}

// ------------------------------------------------------------ prep kernel
// One dispatch: blocks [0,8192) = x f32->bf16 cvt; [8192,12288) = Wq|Wk|Wv
// transpose into wqkvT; [12288,14336) = Wo transpose into woT.
// Transposes: 64x64 tiles, 16B/lane both directions, LDS 144B pitch + XOR.
__global__ __launch_bounds__(256) void prep_kernel(
    const float* __restrict__ x, const float* __restrict__ Wq,
    const float* __restrict__ Wk, const float* __restrict__ Wv,
    const float* __restrict__ Wo, bf16_t* __restrict__ xb,
    bf16_t* __restrict__ wqkvT, bf16_t* __restrict__ woT) {
  __shared__ bf16_t T[64 * 72];
  int bid = blockIdx.x;
  if (bid < 8192) {
    const int i = bid * 256 + threadIdx.x;
    float4 v = ((const float4*)x)[i];
    bf16x4 o = {(bf16_t)v.x, (bf16_t)v.y, (bf16_t)v.z, (bf16_t)v.w};
    *(bf16x4*)(xb + (size_t)i * 4) = o;
    return;
  }
  bid -= 8192;
  const float* ip;
  bf16_t* op;
  int R, C, r0, c0;
  if (bid < 4096) {
    const int zg = bid >> 7, rest = bid & 127;
    r0 = (rest >> 2) * 64;
    c0 = (rest & 3) * 64;
    ip = (zg < 16) ? (Wq + (size_t)zg * SD * SH)
       : (zg < 24) ? (Wk + (size_t)(zg - 16) * SD * SH)
                   : (Wv + (size_t)(zg - 24) * SD * SH);
    op = wqkvT + (size_t)zg * SD * SH;
    R = SD; C = SH;
  } else {
    bid -= 4096;
    r0 = (bid >> 5) * 64;
    c0 = (bid & 31) * 64;
    ip = Wo; op = woT; R = SNQ * SH; C = SD;
  }
  const int tc = threadIdx.x & 15;
  const int tr = threadIdx.x >> 4;
#pragma unroll
  for (int i = 0; i < 4; ++i) {
    const int r = tr + i * 16;
    float4 v = *(const float4*)(ip + (size_t)(r0 + r) * C + c0 + tc * 4);
    float vv[4] = {v.x, v.y, v.z, v.w};
#pragma unroll
    for (int e = 0; e < 4; ++e) {
      const int row = tc * 4 + e;
      *(bf16_t*)((char*)T + row * 144 + ((r * 2) ^ (((row >> 3) & 7) << 4))) =
          (bf16_t)vv[e];
    }
  }
  __syncthreads();
  const int tc2 = threadIdx.x & 7, tr2 = threadIdx.x >> 3;
#pragma unroll
  for (int i = 0; i < 2; ++i) {
    const int row = tr2 + i * 32;
    bf16x8 v = *(const bf16x8*)((const char*)T + row * 144 +
                                ((tc2 * 16) ^ (((row >> 3) & 7) << 4)));
    *(bf16x8*)(op + (size_t)(c0 + row) * R + r0 + tc2 * 8) = v;
  }
}

// ---------------------------------------- GEMM 8-phase (T2+T3+T4+T5)
// BM=256, BN in {256,128}, BK=64, 8 waves (WMxWN), 2-deep LDS dbuf.
// R17 schedule (measured best across R14-R20 variants): B-frags read once
// at phase 0; t+1 half-tile stages staggered one-per-phase; counted vmcnt
// (vmcnt(4) before ph1-end barrier, vmcnt(2) before ph3-end barrier);
// 2 barriers per K-tile. LDS swizzle: slot ^= (row&7), 128B pitch.
// MODE: 1 = fused QKV: bx<16 -> Q to qkv; bx in [16,24) -> RoPE'd K to kb;
//       bx in [24,32) -> V transposed via LDS epilogue to vt. 2 = f32 out.
template <int BN, int MODE>
__global__ __launch_bounds__(512, 1) void gemm8p(const bf16_t* __restrict__ A,
                                                 const bf16_t* __restrict__ Bt,
                                                 void* __restrict__ Cout,
                                                 bf16_t* __restrict__ kbp,
                                                 bf16_t* __restrict__ vtp,
                                                 int M, int N, int K) {
  constexpr int WM = (BN == 256) ? 2 : 4;
  constexpr int WN = 8 / WM;
  constexpr int MQ = 4 / WM;          // m-frags per phase (2 or 1)
  constexpr int BH = BN / 128;        // B half-tiles per K-tile (2 or 1)
  constexpr int SMEM = 65536 + BH * 32768;
  __shared__ char smem[SMEM];
  bf16_t* AsBase = (bf16_t*)smem;              // 2 x 32 KB
  bf16_t* BsBase = (bf16_t*)(smem + 65536);    // 2 x 32|16 KB

  const int tid = threadIdx.x, lane = tid & 63, wid = tid >> 6;
  const int xcd = blockIdx.x & 7, ii = blockIdx.x >> 3;
  int by, bx;
  if (BN == 256) { by = (xcd & 1) * 8 + (ii >> 3); bx = (xcd >> 1) * 8 + (ii & 7); }
  else           { by = (xcd & 3) * 4 + (ii >> 3); bx = (xcd >> 2) * 8 + (ii & 7); }
  const int row0 = by << 8, col0 = bx * BN;
  const int wr = wid / WN, wc = wid % WN;
  const int lr = lane & 15, hi = lane >> 4;

  const bf16_t* Arow = A + (size_t)row0 * K;
  const bf16_t* Brow = Bt + (size_t)col0 * K;

  auto stageHA = [&](int t, int h) {
#pragma unroll
    for (int i = 0; i < 2; ++i) {
      const int f = tid + (i << 9);
      const int r = (h << 7) + (f >> 3), pc = f & 7;
      async_ld16(Arow + (size_t)r * K + (t << 6) + (pc ^ (r & 7)) * 8,
                 (char*)(AsBase + (t & 1) * (256 * 64)) + (h << 14) + f * 16);
    }
  };
  auto stageHB = [&](int t, int h) {
#pragma unroll
    for (int i = 0; i < 2; ++i) {
      const int f = tid + (i << 9);
      const int r = (h << 7) + (f >> 3), pc = f & 7;
      async_ld16(Brow + (size_t)r * K + (t << 6) + (pc ^ (r & 7)) * 8,
                 (char*)(BsBase + (t & 1) * (BN * 64)) + (h << 14) + f * 16);
    }
  };

  f32x4 acc[4 * MQ][4];
#pragma unroll
  for (int m = 0; m < 4 * MQ; ++m)
#pragma unroll
    for (int n = 0; n < 4; ++n) acc[m][n] = f32x4{0.f, 0.f, 0.f, 0.f};

  const int NT = K >> 6;
  stageHB(0, 0);
  if (BH == 2) stageHB(0, 1);
  stageHA(0, 0); stageHA(0, 1);
  asm volatile("s_waitcnt vmcnt(2)" ::: "memory");
  __builtin_amdgcn_s_barrier();
  __builtin_amdgcn_sched_barrier(0);

  for (int t = 0; t < NT; ++t) {
    const bool pre = (t + 1 < NT);
    const char* Ab = (const char*)(AsBase + (t & 1) * (256 * 64));
    const char* Bb = (const char*)(BsBase + (t & 1) * (BN * 64));
    bf16x8 bfr[4][2];

#pragma unroll
    for (int q = 0; q < 4; ++q) {
      if (q == 0) {
#pragma unroll
        for (int nf = 0; nf < 4; ++nf)
#pragma unroll
          for (int ks = 0; ks < 2; ++ks) {
            const int r = nf * (16 * WN) + wc * 16 + lr;
            bfr[nf][ks] = *(const bf16x8*)(Bb + r * 128 +
                                           ((((ks << 2) + hi) ^ (r & 7)) << 4));
          }
      }
      bf16x8 af[MQ][2];
#pragma unroll
      for (int mq = 0; mq < MQ; ++mq)
#pragma unroll
        for (int ks = 0; ks < 2; ++ks) {
          const int r = q * 64 + mq * (16 * WM) + wr * 16 + lr;
          af[mq][ks] = *(const bf16x8*)(Ab + r * 128 +
                                        ((((ks << 2) + hi) ^ (r & 7)) << 4));
        }
      // stagger next tile's half-tile stages one-per-phase (R17 schedule)
      if (pre) {
        if (BH == 2) {
          if (q == 0) stageHB(t + 1, 0);
          if (q == 1) stageHB(t + 1, 1);
          if (q == 2) stageHA(t + 1, 0);
          if (q == 3) stageHA(t + 1, 1);
        } else {
          if (q == 0) stageHB(t + 1, 0);
          if (q == 1) stageHA(t + 1, 0);
          if (q == 2) stageHA(t + 1, 1);
        }
      }
      __builtin_amdgcn_s_setprio(1);
#pragma unroll
      for (int mq = 0; mq < MQ; ++mq)
#pragma unroll
        for (int nf = 0; nf < 4; ++nf)
#pragma unroll
          for (int ks = 0; ks < 2; ++ks)
            acc[q * MQ + mq][nf] = __builtin_amdgcn_mfma_f32_16x16x32_bf16(
                af[mq][ks], bfr[nf][ks], acc[q * MQ + mq][nf], 0, 0, 0);
      __builtin_amdgcn_s_setprio(0);
      if (q == 1) {
        if (pre) asm volatile("s_waitcnt vmcnt(4)" ::: "memory");
        else     asm volatile("s_waitcnt vmcnt(0)" ::: "memory");
        __builtin_amdgcn_s_barrier();
        __builtin_amdgcn_sched_barrier(0);
      }
      if (q == 3 && pre) {
        asm volatile("s_waitcnt vmcnt(2)" ::: "memory");
        __builtin_amdgcn_s_barrier();
        __builtin_amdgcn_sched_barrier(0);
      }
    }
  }

  // ---------------- epilogue ----------------
  if (MODE == 1 && bx >= 16 && bx < 24) {
    // K-head block: apply RoPE in-register, write to kb [B][NKV][S][H].
    const int kv = bx - 16;
#pragma unroll
    for (int mf = 0; mf < 4 * MQ; ++mf) {
      const int r = row0 + (mf / MQ) * 64 + (mf % MQ) * (16 * WM) + wr * 16 + hi * 4;
#pragma unroll
      for (int nfp = 0; nfp < 2; ++nfp) {
        const int h = nfp * 64 + wc * 16 + lr;   // 0..127
        const float inv = __expf((float)h * -0.07195578f);
#pragma unroll
        for (int j = 0; j < 4; ++j) {
          const int rg = r + j;
          const int tpos = rg & (SS - 1), b = rg >> 11;
          const float fr = (float)tpos * inv;
          const float cs = __cosf(fr), sn = __sinf(fr);
          const float x1 = acc[mf][nfp][j], x2 = acc[mf][nfp + 2][j];
          bf16_t* kp = kbp + ((size_t)(b * SNKV + kv) * SS + tpos) * SH + h;
          kp[0] = (bf16_t)(x1 * cs - x2 * sn);
          kp[128] = (bf16_t)(x2 * cs + x1 * sn);
        }
      }
    }
  } else if (MODE == 1 && bx >= 24) {
    // V-head block: transpose 256(t) x 256(h) via LDS, write vt coalesced.
    bf16_t* T = (bf16_t*)smem;
    __syncthreads();
    const int kv = bx - 24;
#pragma unroll
    for (int mf = 0; mf < 4 * MQ; ++mf) {
      const int tl = (mf / MQ) * 64 + (mf % MQ) * (16 * WM) + wr * 16 + hi * 4;
#pragma unroll
      for (int nf = 0; nf < 4; ++nf) {
        const int h = nf * (16 * WN) + wc * 16 + lr;
        bf16x4 v4 = {(bf16_t)acc[mf][nf][0], (bf16_t)acc[mf][nf][1],
                     (bf16_t)acc[mf][nf][2], (bf16_t)acc[mf][nf][3]};
        *(bf16x4*)((char*)T + h * 512 + ((tl * 2) ^ ((h & 7) << 4))) = v4;
      }
    }
    __syncthreads();
    const int b = row0 >> 11, t0b = row0 & (SS - 1);
    bf16_t* vbase = vtp + (size_t)(b * SNKV + kv) * SH * SS;
#pragma unroll
    for (int it = 0; it < 16; ++it) {
      const int f = tid + (it << 9);         // 0..8191
      const int h = f >> 5, sl = f & 31;
      bf16x8 v = *(const bf16x8*)((const char*)T + h * 512 +
                                  ((sl << 4) ^ ((h & 7) << 4)));
      *(bf16x8*)(vbase + (size_t)h * SS + t0b + sl * 8) = v;
    }
  } else {
#pragma unroll
    for (int mf = 0; mf < 4 * MQ; ++mf) {
      const int r = row0 + (mf / MQ) * 64 + (mf % MQ) * (16 * WM) + wr * 16 + hi * 4;
#pragma unroll
      for (int nf = 0; nf < 4; ++nf) {
        const int c = col0 + nf * (16 * WN) + wc * 16 + lr;
#pragma unroll
        for (int j = 0; j < 4; ++j) {
          if (MODE == 2)
            ((float*)Cout)[(size_t)(r + j) * N + c] = acc[mf][nf][j];
          else
            ((bf16_t*)Cout)[(size_t)(r + j) * N + c] = (bf16_t)acc[mf][nf][j];
        }
      }
    }
  }
}

// -------------------------------------------------------------- attention
// R7 structure; QK/softcap pair-interleaved: {16-MFMA chain for nt-pair p
// -> softcap+P-write pair p} x2, so pair 0's exp overlaps pair 1's MFMAs
// (chain-latency relief; attn is dependency-bound: 17% occupancy, ~11k
// cyc/tile vs ~3k pipe model). launch_bounds (512,1): LDS already caps at
// 1 block/CU, so the looser bound only frees the register allocator.
#define QB 128
#define KVB 64
#define PP 72    // Ps pitch 144B

__global__ __launch_bounds__(512, 1) void attn_kernel(
    const bf16_t* __restrict__ Q,   // [B*S][QKVP] (RAW fused projection)
    const bf16_t* __restrict__ Kt,  // [B][NKV][S][H] (roped)
    const bf16_t* __restrict__ Vt,  // [B][NKV][H][S]
    bf16_t* __restrict__ AV) {      // [B*S][NQ*H]
  __shared__ bf16_t Ks[2][KVB * SH];   // 2 x 32 KB, row pitch 512B
  __shared__ bf16_t Vs[2][SH * KVB];   // 2 x 32 KB, row pitch 128B
  __shared__ bf16_t Ps[QB * PP];       // 18 KB

  const int tid = threadIdx.x, lane = tid & 63, wid = tid >> 6;
  const int x = blockIdx.x & 7;
  const int y = blockIdx.x >> 3;       // 0..63
  const int qt = 15 - (y & 15);        // heavy tiles dispatch first
  const int head = (x << 1) | ((y >> 4) & 1);
  const int b = y >> 5;
  const int kvh = x;
  const int t0 = qt << 7;
  const int trw = t0 + wid * 16;       // this wave's first q row
  const int lr = lane & 15, hi = lane >> 4;
  const int lk = hi << 3;
  const int lq = hi;

  // Q load + fused RoPE + 1/16 scale (pair (c, c+128) = qf[ks], qf[ks+4])
  bf16x8 qf[8];
  {
    const bf16_t* qp = Q + ((size_t)(b * SS + trw + lr)) * QKVP + head * SH + lk;
#pragma unroll
    for (int ks = 0; ks < 8; ++ks) qf[ks] = *(const bf16x8*)(qp + ks * 32);
    const float tpos = (float)(trw + lr);
#pragma unroll
    for (int ks = 0; ks < 4; ++ks) {
      bf16x8 a = qf[ks], b2 = qf[ks + 4];
      bf16x8 ra, rb;
#pragma unroll
      for (int e = 0; e < 8; ++e) {
        float c_ = (float)(ks * 32 + lk + e);
        float inv = __expf(c_ * -0.07195578f);
        float fr = tpos * inv;
        float cs = __cosf(fr), sn = __sinf(fr);
        float x1 = (float)a[e], x2 = (float)b2[e];
        ra[e] = (bf16_t)((x1 * cs - x2 * sn) * 0.0625f);
        rb[e] = (bf16_t)((x2 * cs + x1 * sn) * 0.0625f);
      }
      qf[ks] = ra; qf[ks + 4] = rb;
    }
  }

  f32x4 o[16];
#pragma unroll
  for (int i = 0; i < 16; ++i) o[i] = f32x4{0.f, 0.f, 0.f, 0.f};
  float lsum[4] = {0.f, 0.f, 0.f, 0.f};

  const bf16_t* Kb = Kt + (size_t)(b * SNKV + kvh) * SS * SH;
  const bf16_t* Vb = Vt + (size_t)(b * SNKV + kvh) * SH * SS;

  const int sv0 = (t0 >= SWIN) ? ((t0 >> 6) - 16) : 0;
  const int sv1 = (t0 >> 6) + 1;

  auto stage = [&](int s0, int d) {
#pragma unroll
    for (int it = 0; it < 4; ++it) {
      const int f = tid + (it << 9);           // 0..2047
      {
        const int r = f >> 5, pc = f & 31;
        const int sc = pc ^ (r & 7);
        async_ld16(Kb + (size_t)(s0 + r) * SH + sc * 8, (char*)Ks[d] + f * 16);
      }
      {
        const int r = f >> 3, pc = f & 7;
        const int sc = pc ^ (r & 7);
        async_ld16(Vb + (size_t)r * SS + s0 + sc * 8, (char*)Vs[d] + f * 16);
      }
    }
  };

  stage(sv0 << 6, 0);
  __syncthreads();

  int cur = 0;
  for (int sv = sv0; sv <= sv1; ++sv, cur ^= 1) {
    if (sv < sv1) stage((sv + 1) << 6, cur ^ 1);

    const int s0 = sv << 6;
    const bool skip = (s0 > trw + 15) || (s0 + 63 < trw - (SWIN - 1));
    if (!skip) {
      const bf16_t* Kc = Ks[cur];
      const bf16_t* Vc = Vs[cur];
      const bool full = (s0 + 63 <= trw) && (s0 >= trw + 15 - (SWIN - 1));

      // QK + softcap, pair-interleaved: pair p = nt {2p, 2p+1}
#pragma unroll
      for (int np = 0; np < 2; ++np) {
        f32x4 sa0 = f32x4{0.f, 0.f, 0.f, 0.f};
        f32x4 sa1 = f32x4{0.f, 0.f, 0.f, 0.f};
        const int R0 = (np * 2) * 16 + lr;
        const int R1 = (np * 2 + 1) * 16 + lr;
        __builtin_amdgcn_s_setprio(1);
#pragma unroll
        for (int ks = 0; ks < 8; ++ks) {
          bf16x8 kf0 = *(const bf16x8*)((const char*)Kc + R0 * 512 +
                                        (((ks * 4 + hi) ^ (R0 & 7)) << 4));
          bf16x8 kf1 = *(const bf16x8*)((const char*)Kc + R1 * 512 +
                                        (((ks * 4 + hi) ^ (R1 & 7)) << 4));
          sa0 = __builtin_amdgcn_mfma_f32_16x16x32_bf16(qf[ks], kf0, sa0, 0, 0, 0);
          sa1 = __builtin_amdgcn_mfma_f32_16x16x32_bf16(qf[ks], kf1, sa1, 0, 0, 0);
        }
        __builtin_amdgcn_s_setprio(0);
        // softcap + exp + P-write for this pair (overlaps next pair's MFMAs)
#pragma unroll
        for (int half = 0; half < 2; ++half) {
          const f32x4 sa = half ? sa1 : sa0;
          const int nt = np * 2 + half;
#pragma unroll
          for (int j = 0; j < 4; ++j) {
            float u = sa[j] * 0.04f;
            float th = 50.f - 100.f * __builtin_amdgcn_rcpf(__expf(u) + 1.f);
            float p;
            if (full) {
              p = __expf(th);
            } else {
              const int s_ = s0 + nt * 16 + lr;
              const int t_ = trw + lq * 4 + j;
              const bool valid = (s_ <= t_) && (t_ - s_ < SWIN);
              p = valid ? __expf(th) : 0.f;
            }
            lsum[j] += p;
            Ps[(wid * 16 + lq * 4 + j) * PP + nt * 16 + lr] = (bf16_t)p;
          }
        }
      }

      // O += P V   (P rows wave-local: lgkmcnt ordering suffices)
      __builtin_amdgcn_s_setprio(1);
#pragma unroll
      for (int ks = 0; ks < 2; ++ks) {
        bf16x8 pf = *(const bf16x8*)&Ps[(wid * 16 + lr) * PP + ks * 32 + lk];
#pragma unroll
        for (int nt = 0; nt < 16; ++nt) {
          const int R = nt * 16 + lr;
          bf16x8 vf = *(const bf16x8*)((const char*)Vc + R * 128 +
                                       (((ks * 4 + hi) ^ (R & 7)) << 4));
          o[nt] = __builtin_amdgcn_mfma_f32_16x16x32_bf16(pf, vf, o[nt], 0, 0, 0);
        }
      }
      __builtin_amdgcn_s_setprio(0);
    }

    __syncthreads();
  }

#pragma unroll
  for (int j = 0; j < 4; ++j) {
    float l = lsum[j];
    l += __shfl_xor(l, 1);
    l += __shfl_xor(l, 2);
    l += __shfl_xor(l, 4);
    l += __shfl_xor(l, 8);
    const float inv = 1.f / l;
    const int t_ = trw + lq * 4 + j;
    bf16_t* op = AV + ((size_t)(b * SS + t_)) * (SNQ * SH) + head * SH;
#pragma unroll
    for (int nt = 0; nt < 16; ++nt) op[nt * 16 + lr] = (bf16_t)(o[nt][j] * inv);
  }
}

// ------------------------------------------------------------------- host
extern "C" void kernel_launch(void* const* d_in, const int* in_sizes, int n_in,
                              void* d_out, int out_size, void* d_ws, size_t ws_size,
                              hipStream_t stream) {
  const float* x = (const float*)d_in[0];
  const float* Wq = (const float*)d_in[1];
  const float* Wk = (const float*)d_in[2];
  const float* Wv = (const float*)d_in[3];
  const float* Wo = (const float*)d_in[4];
  float* out = (float*)d_out;

  char* ws = (char*)d_ws;
  size_t off = 0;
  auto alloc = [&](size_t elems) {
    bf16_t* p = (bf16_t*)(ws + off);
    off += ((elems * 2 + 255) & ~(size_t)255);
    return p;
  };
  const size_t MS = (size_t)SB * SS;        // 4096 rows
  bf16_t* xb     = alloc(MS * SD);                 // [4096][2048]
  bf16_t* wqkvT  = alloc((size_t)QKVP * SD);       // [8192][2048]: Wq|Wk|Wv
  bf16_t* woT    = alloc((size_t)SD * SNQ * SH);   // [2048][4096]
  bf16_t* qkv    = alloc(MS * QKVP);               // [4096][8192]: Q|·|·
  bf16_t* kb     = alloc(MS * SNKV * SH);          // [B][NKV][S][H] (roped)
  bf16_t* vt     = alloc(MS * SNKV * SH);          // [B][NKV][H][S]
  bf16_t* av     = alloc(MS * SNQ * SH);           // [4096][4096]
  (void)ws_size;  // ~178 MB

  prep_kernel<<<14336, 256, 0, stream>>>(x, Wq, Wk, Wv, Wo, xb, wqkvT, woT);

  // fused Q|K|V projection; K roped -> kb, V transposed -> vt (epilogues)
  gemm8p<256, 1><<<512, 512, 0, stream>>>(xb, wqkvT, qkv, kb, vt, 4096, QKVP, 2048);

  attn_kernel<<<512, 512, 0, stream>>>(qkv, kb, vt, av);

  // O-proj: [4096x4096] x [2048x4096]^T -> [4096][2048] f32, 256 blocks
  gemm8p<128, 2><<<256, 512, 0, stream>>>(av, woT, out, nullptr, nullptr, 4096, 2048, 4096);
}

// Round 23
// 322.294 us; speedup vs baseline: 1.0201x; 1.0201x over previous
//
#include <hip/hip_runtime.h>
#include <stdint.h>

typedef __bf16 bf16_t;
typedef __bf16 bf16x8 __attribute__((ext_vector_type(8)));
typedef __bf16 bf16x4 __attribute__((ext_vector_type(4)));
typedef float f32x4 __attribute__((ext_vector_type(4)));

#define DEV static __device__ __forceinline__

// problem constants
#define SB 2
#define SS 2048
#define SD 2048
#define SNQ 16
#define SNKV 8
#define SH 256
#define SWIN 1024
#define QKVP 8192   // fused projection output pitch (Q | K | V)

DEV void async_ld16(const void* g, void* lds) {
  __builtin_amdgcn_global_load_lds(
      (const __attribute__((address_space(1))) void*)g,
      (__attribute__((address_space(3))) void*)lds, 16, 0, 0);
}

// ------------------------------------------------------------ prep kernel
// One dispatch: blocks [0,8192) = x f32->bf16 cvt; [8192,12288) = Wq|Wk|Wv
// transpose into wqkvT; [12288,14336) = Wo transpose into woT.
// Transposes: 64x64 tiles, 16B/lane both directions, LDS 144B pitch + XOR.
__global__ __launch_bounds__(256) void prep_kernel(
    const float* __restrict__ x, const float* __restrict__ Wq,
    const float* __restrict__ Wk, const float* __restrict__ Wv,
    const float* __restrict__ Wo, bf16_t* __restrict__ xb,
    bf16_t* __restrict__ wqkvT, bf16_t* __restrict__ woT) {
  __shared__ bf16_t T[64 * 72];
  int bid = blockIdx.x;
  if (bid < 8192) {
    const int i = bid * 256 + threadIdx.x;
    float4 v = ((const float4*)x)[i];
    bf16x4 o = {(bf16_t)v.x, (bf16_t)v.y, (bf16_t)v.z, (bf16_t)v.w};
    *(bf16x4*)(xb + (size_t)i * 4) = o;
    return;
  }
  bid -= 8192;
  const float* ip;
  bf16_t* op;
  int R, C, r0, c0;
  if (bid < 4096) {
    const int zg = bid >> 7, rest = bid & 127;
    r0 = (rest >> 2) * 64;
    c0 = (rest & 3) * 64;
    ip = (zg < 16) ? (Wq + (size_t)zg * SD * SH)
       : (zg < 24) ? (Wk + (size_t)(zg - 16) * SD * SH)
                   : (Wv + (size_t)(zg - 24) * SD * SH);
    op = wqkvT + (size_t)zg * SD * SH;
    R = SD; C = SH;
  } else {
    bid -= 4096;
    r0 = (bid >> 5) * 64;
    c0 = (bid & 31) * 64;
    ip = Wo; op = woT; R = SNQ * SH; C = SD;
  }
  const int tc = threadIdx.x & 15;
  const int tr = threadIdx.x >> 4;
#pragma unroll
  for (int i = 0; i < 4; ++i) {
    const int r = tr + i * 16;
    float4 v = *(const float4*)(ip + (size_t)(r0 + r) * C + c0 + tc * 4);
    float vv[4] = {v.x, v.y, v.z, v.w};
#pragma unroll
    for (int e = 0; e < 4; ++e) {
      const int row = tc * 4 + e;
      *(bf16_t*)((char*)T + row * 144 + ((r * 2) ^ (((row >> 3) & 7) << 4))) =
          (bf16_t)vv[e];
    }
  }
  __syncthreads();
  const int tc2 = threadIdx.x & 7, tr2 = threadIdx.x >> 3;
#pragma unroll
  for (int i = 0; i < 2; ++i) {
    const int row = tr2 + i * 32;
    bf16x8 v = *(const bf16x8*)((const char*)T + row * 144 +
                                ((tc2 * 16) ^ (((row >> 3) & 7) << 4)));
    *(bf16x8*)(op + (size_t)(c0 + row) * R + r0 + tc2 * 8) = v;
  }
}

// ---------------------------------------- GEMM 8-phase (T2+T3+T4+T5)
// BM=256, BN in {256,128}, BK=64, 8 waves (WMxWN), 2-deep LDS dbuf.
// R17 schedule (measured best across R14-R20 variants): B-frags read once
// at phase 0; t+1 half-tile stages staggered one-per-phase; counted vmcnt
// (vmcnt(4) before ph1-end barrier, vmcnt(2) before ph3-end barrier);
// 2 barriers per K-tile. LDS swizzle: slot ^= (row&7), 128B pitch.
// MODE: 1 = fused QKV: bx<16 -> Q to qkv; bx in [16,24) -> RoPE'd K to kb;
//       bx in [24,32) -> V transposed via LDS epilogue to vt. 2 = f32 out.
template <int BN, int MODE>
__global__ __launch_bounds__(512, 1) void gemm8p(const bf16_t* __restrict__ A,
                                                 const bf16_t* __restrict__ Bt,
                                                 void* __restrict__ Cout,
                                                 bf16_t* __restrict__ kbp,
                                                 bf16_t* __restrict__ vtp,
                                                 int M, int N, int K) {
  constexpr int WM = (BN == 256) ? 2 : 4;
  constexpr int WN = 8 / WM;
  constexpr int MQ = 4 / WM;          // m-frags per phase (2 or 1)
  constexpr int BH = BN / 128;        // B half-tiles per K-tile (2 or 1)
  constexpr int SMEM = 65536 + BH * 32768;
  __shared__ char smem[SMEM];
  bf16_t* AsBase = (bf16_t*)smem;              // 2 x 32 KB
  bf16_t* BsBase = (bf16_t*)(smem + 65536);    // 2 x 32|16 KB

  const int tid = threadIdx.x, lane = tid & 63, wid = tid >> 6;
  const int xcd = blockIdx.x & 7, ii = blockIdx.x >> 3;
  int by, bx;
  if (BN == 256) { by = (xcd & 1) * 8 + (ii >> 3); bx = (xcd >> 1) * 8 + (ii & 7); }
  else           { by = (xcd & 3) * 4 + (ii >> 3); bx = (xcd >> 2) * 8 + (ii & 7); }
  const int row0 = by << 8, col0 = bx * BN;
  const int wr = wid / WN, wc = wid % WN;
  const int lr = lane & 15, hi = lane >> 4;

  const bf16_t* Arow = A + (size_t)row0 * K;
  const bf16_t* Brow = Bt + (size_t)col0 * K;

  auto stageHA = [&](int t, int h) {
#pragma unroll
    for (int i = 0; i < 2; ++i) {
      const int f = tid + (i << 9);
      const int r = (h << 7) + (f >> 3), pc = f & 7;
      async_ld16(Arow + (size_t)r * K + (t << 6) + (pc ^ (r & 7)) * 8,
                 (char*)(AsBase + (t & 1) * (256 * 64)) + (h << 14) + f * 16);
    }
  };
  auto stageHB = [&](int t, int h) {
#pragma unroll
    for (int i = 0; i < 2; ++i) {
      const int f = tid + (i << 9);
      const int r = (h << 7) + (f >> 3), pc = f & 7;
      async_ld16(Brow + (size_t)r * K + (t << 6) + (pc ^ (r & 7)) * 8,
                 (char*)(BsBase + (t & 1) * (BN * 64)) + (h << 14) + f * 16);
    }
  };

  f32x4 acc[4 * MQ][4];
#pragma unroll
  for (int m = 0; m < 4 * MQ; ++m)
#pragma unroll
    for (int n = 0; n < 4; ++n) acc[m][n] = f32x4{0.f, 0.f, 0.f, 0.f};

  const int NT = K >> 6;
  stageHB(0, 0);
  if (BH == 2) stageHB(0, 1);
  stageHA(0, 0); stageHA(0, 1);
  asm volatile("s_waitcnt vmcnt(2)" ::: "memory");
  __builtin_amdgcn_s_barrier();
  __builtin_amdgcn_sched_barrier(0);

  for (int t = 0; t < NT; ++t) {
    const bool pre = (t + 1 < NT);
    const char* Ab = (const char*)(AsBase + (t & 1) * (256 * 64));
    const char* Bb = (const char*)(BsBase + (t & 1) * (BN * 64));
    bf16x8 bfr[4][2];

#pragma unroll
    for (int q = 0; q < 4; ++q) {
      if (q == 0) {
#pragma unroll
        for (int nf = 0; nf < 4; ++nf)
#pragma unroll
          for (int ks = 0; ks < 2; ++ks) {
            const int r = nf * (16 * WN) + wc * 16 + lr;
            bfr[nf][ks] = *(const bf16x8*)(Bb + r * 128 +
                                           ((((ks << 2) + hi) ^ (r & 7)) << 4));
          }
      }
      bf16x8 af[MQ][2];
#pragma unroll
      for (int mq = 0; mq < MQ; ++mq)
#pragma unroll
        for (int ks = 0; ks < 2; ++ks) {
          const int r = q * 64 + mq * (16 * WM) + wr * 16 + lr;
          af[mq][ks] = *(const bf16x8*)(Ab + r * 128 +
                                        ((((ks << 2) + hi) ^ (r & 7)) << 4));
        }
      // stagger next tile's half-tile stages one-per-phase (R17 schedule)
      if (pre) {
        if (BH == 2) {
          if (q == 0) stageHB(t + 1, 0);
          if (q == 1) stageHB(t + 1, 1);
          if (q == 2) stageHA(t + 1, 0);
          if (q == 3) stageHA(t + 1, 1);
        } else {
          if (q == 0) stageHB(t + 1, 0);
          if (q == 1) stageHA(t + 1, 0);
          if (q == 2) stageHA(t + 1, 1);
        }
      }
      __builtin_amdgcn_s_setprio(1);
#pragma unroll
      for (int mq = 0; mq < MQ; ++mq)
#pragma unroll
        for (int nf = 0; nf < 4; ++nf)
#pragma unroll
          for (int ks = 0; ks < 2; ++ks)
            acc[q * MQ + mq][nf] = __builtin_amdgcn_mfma_f32_16x16x32_bf16(
                af[mq][ks], bfr[nf][ks], acc[q * MQ + mq][nf], 0, 0, 0);
      __builtin_amdgcn_s_setprio(0);
      if (q == 1) {
        if (pre) asm volatile("s_waitcnt vmcnt(4)" ::: "memory");
        else     asm volatile("s_waitcnt vmcnt(0)" ::: "memory");
        __builtin_amdgcn_s_barrier();
        __builtin_amdgcn_sched_barrier(0);
      }
      if (q == 3 && pre) {
        asm volatile("s_waitcnt vmcnt(2)" ::: "memory");
        __builtin_amdgcn_s_barrier();
        __builtin_amdgcn_sched_barrier(0);
      }
    }
  }

  // ---------------- epilogue ----------------
  if (MODE == 1 && bx >= 16 && bx < 24) {
    // K-head block: apply RoPE in-register, write to kb [B][NKV][S][H].
    const int kv = bx - 16;
#pragma unroll
    for (int mf = 0; mf < 4 * MQ; ++mf) {
      const int r = row0 + (mf / MQ) * 64 + (mf % MQ) * (16 * WM) + wr * 16 + hi * 4;
#pragma unroll
      for (int nfp = 0; nfp < 2; ++nfp) {
        const int h = nfp * 64 + wc * 16 + lr;   // 0..127
        const float inv = __expf((float)h * -0.07195578f);
#pragma unroll
        for (int j = 0; j < 4; ++j) {
          const int rg = r + j;
          const int tpos = rg & (SS - 1), b = rg >> 11;
          const float fr = (float)tpos * inv;
          const float cs = __cosf(fr), sn = __sinf(fr);
          const float x1 = acc[mf][nfp][j], x2 = acc[mf][nfp + 2][j];
          bf16_t* kp = kbp + ((size_t)(b * SNKV + kv) * SS + tpos) * SH + h;
          kp[0] = (bf16_t)(x1 * cs - x2 * sn);
          kp[128] = (bf16_t)(x2 * cs + x1 * sn);
        }
      }
    }
  } else if (MODE == 1 && bx >= 24) {
    // V-head block: transpose 256(t) x 256(h) via LDS, write vt coalesced.
    bf16_t* T = (bf16_t*)smem;
    __syncthreads();
    const int kv = bx - 24;
#pragma unroll
    for (int mf = 0; mf < 4 * MQ; ++mf) {
      const int tl = (mf / MQ) * 64 + (mf % MQ) * (16 * WM) + wr * 16 + hi * 4;
#pragma unroll
      for (int nf = 0; nf < 4; ++nf) {
        const int h = nf * (16 * WN) + wc * 16 + lr;
        bf16x4 v4 = {(bf16_t)acc[mf][nf][0], (bf16_t)acc[mf][nf][1],
                     (bf16_t)acc[mf][nf][2], (bf16_t)acc[mf][nf][3]};
        *(bf16x4*)((char*)T + h * 512 + ((tl * 2) ^ ((h & 7) << 4))) = v4;
      }
    }
    __syncthreads();
    const int b = row0 >> 11, t0b = row0 & (SS - 1);
    bf16_t* vbase = vtp + (size_t)(b * SNKV + kv) * SH * SS;
#pragma unroll
    for (int it = 0; it < 16; ++it) {
      const int f = tid + (it << 9);         // 0..8191
      const int h = f >> 5, sl = f & 31;
      bf16x8 v = *(const bf16x8*)((const char*)T + h * 512 +
                                  ((sl << 4) ^ ((h & 7) << 4)));
      *(bf16x8*)(vbase + (size_t)h * SS + t0b + sl * 8) = v;
    }
  } else {
#pragma unroll
    for (int mf = 0; mf < 4 * MQ; ++mf) {
      const int r = row0 + (mf / MQ) * 64 + (mf % MQ) * (16 * WM) + wr * 16 + hi * 4;
#pragma unroll
      for (int nf = 0; nf < 4; ++nf) {
        const int c = col0 + nf * (16 * WN) + wc * 16 + lr;
#pragma unroll
        for (int j = 0; j < 4; ++j) {
          if (MODE == 2)
            ((float*)Cout)[(size_t)(r + j) * N + c] = acc[mf][nf][j];
          else
            ((bf16_t*)Cout)[(size_t)(r + j) * N + c] = (bf16_t)acc[mf][nf][j];
        }
      }
    }
  }
}

// -------------------------------------------------------------- attention
// R7 kernel (best measured: ~124 us across R7/R13/R19/R21; seven structural
// variants R8-R12/R22 all regressed). 8 waves x 16 q-rows, KVB=64 dbuf,
// RoPE-Q fused into Q load, fixed-base softmax (softcap bounds logits to
// +-50 -> no online max/rescale), both-sides XOR swizzles, LPT dispatch.
#define QB 128
#define KVB 64
#define PP 72    // Ps pitch 144B

__global__ __launch_bounds__(512, 2) void attn_kernel(
    const bf16_t* __restrict__ Q,   // [B*S][QKVP] (RAW fused projection)
    const bf16_t* __restrict__ Kt,  // [B][NKV][S][H] (roped)
    const bf16_t* __restrict__ Vt,  // [B][NKV][H][S]
    bf16_t* __restrict__ AV) {      // [B*S][NQ*H]
  __shared__ bf16_t Ks[2][KVB * SH];   // 2 x 32 KB, row pitch 512B
  __shared__ bf16_t Vs[2][SH * KVB];   // 2 x 32 KB, row pitch 128B
  __shared__ bf16_t Ps[QB * PP];       // 18 KB

  const int tid = threadIdx.x, lane = tid & 63, wid = tid >> 6;
  const int x = blockIdx.x & 7;
  const int y = blockIdx.x >> 3;       // 0..63
  const int qt = 15 - (y & 15);        // heavy tiles dispatch first
  const int head = (x << 1) | ((y >> 4) & 1);
  const int b = y >> 5;
  const int kvh = x;
  const int t0 = qt << 7;
  const int trw = t0 + wid * 16;       // this wave's first q row
  const int lr = lane & 15, hi = lane >> 4;
  const int lk = hi << 3;
  const int lq = hi;

  // Q load + fused RoPE + 1/16 scale (pair (c, c+128) = qf[ks], qf[ks+4])
  bf16x8 qf[8];
  {
    const bf16_t* qp = Q + ((size_t)(b * SS + trw + lr)) * QKVP + head * SH + lk;
#pragma unroll
    for (int ks = 0; ks < 8; ++ks) qf[ks] = *(const bf16x8*)(qp + ks * 32);
    const float tpos = (float)(trw + lr);
#pragma unroll
    for (int ks = 0; ks < 4; ++ks) {
      bf16x8 a = qf[ks], b2 = qf[ks + 4];
      bf16x8 ra, rb;
#pragma unroll
      for (int e = 0; e < 8; ++e) {
        float c_ = (float)(ks * 32 + lk + e);
        float inv = __expf(c_ * -0.07195578f);
        float fr = tpos * inv;
        float cs = __cosf(fr), sn = __sinf(fr);
        float x1 = (float)a[e], x2 = (float)b2[e];
        ra[e] = (bf16_t)((x1 * cs - x2 * sn) * 0.0625f);
        rb[e] = (bf16_t)((x2 * cs + x1 * sn) * 0.0625f);
      }
      qf[ks] = ra; qf[ks + 4] = rb;
    }
  }

  f32x4 o[16];
#pragma unroll
  for (int i = 0; i < 16; ++i) o[i] = f32x4{0.f, 0.f, 0.f, 0.f};
  float lsum[4] = {0.f, 0.f, 0.f, 0.f};

  const bf16_t* Kb = Kt + (size_t)(b * SNKV + kvh) * SS * SH;
  const bf16_t* Vb = Vt + (size_t)(b * SNKV + kvh) * SH * SS;

  const int sv0 = (t0 >= SWIN) ? ((t0 >> 6) - 16) : 0;
  const int sv1 = (t0 >> 6) + 1;

  auto stage = [&](int s0, int d) {
#pragma unroll
    for (int it = 0; it < 4; ++it) {
      const int f = tid + (it << 9);           // 0..2047
      {
        const int r = f >> 5, pc = f & 31;
        const int sc = pc ^ (r & 7);
        async_ld16(Kb + (size_t)(s0 + r) * SH + sc * 8, (char*)Ks[d] + f * 16);
      }
      {
        const int r = f >> 3, pc = f & 7;
        const int sc = pc ^ (r & 7);
        async_ld16(Vb + (size_t)r * SS + s0 + sc * 8, (char*)Vs[d] + f * 16);
      }
    }
  };

  stage(sv0 << 6, 0);
  __syncthreads();

  int cur = 0;
  for (int sv = sv0; sv <= sv1; ++sv, cur ^= 1) {
    if (sv < sv1) stage((sv + 1) << 6, cur ^ 1);

    const int s0 = sv << 6;
    const bool skip = (s0 > trw + 15) || (s0 + 63 < trw - (SWIN - 1));
    if (!skip) {
      const bf16_t* Kc = Ks[cur];
      const bf16_t* Vc = Vs[cur];
      f32x4 sacc[4];
#pragma unroll
      for (int nt = 0; nt < 4; ++nt) sacc[nt] = f32x4{0.f, 0.f, 0.f, 0.f};
      __builtin_amdgcn_s_setprio(1);
#pragma unroll
      for (int ks = 0; ks < 8; ++ks) {
#pragma unroll
        for (int nt = 0; nt < 4; ++nt) {
          const int R = nt * 16 + lr;
          bf16x8 kf = *(const bf16x8*)((const char*)Kc + R * 512 +
                                       (((ks * 4 + hi) ^ (R & 7)) << 4));
          sacc[nt] = __builtin_amdgcn_mfma_f32_16x16x32_bf16(qf[ks], kf, sacc[nt], 0, 0, 0);
        }
      }
      __builtin_amdgcn_s_setprio(0);

      const bool full = (s0 + 63 <= trw) && (s0 >= trw + 15 - (SWIN - 1));
      if (full) {
#pragma unroll
        for (int nt = 0; nt < 4; ++nt) {
#pragma unroll
          for (int j = 0; j < 4; ++j) {
            float u = sacc[nt][j] * 0.04f;
            float th = 50.f - 100.f * __builtin_amdgcn_rcpf(__expf(u) + 1.f);
            float p = __expf(th);
            lsum[j] += p;
            Ps[(wid * 16 + lq * 4 + j) * PP + nt * 16 + lr] = (bf16_t)p;
          }
        }
      } else {
#pragma unroll
        for (int nt = 0; nt < 4; ++nt) {
          const int s_ = s0 + nt * 16 + lr;
#pragma unroll
          for (int j = 0; j < 4; ++j) {
            const int t_ = trw + lq * 4 + j;
            float u = sacc[nt][j] * 0.04f;
            float th = 50.f - 100.f * __builtin_amdgcn_rcpf(__expf(u) + 1.f);
            const bool valid = (s_ <= t_) && (t_ - s_ < SWIN);
            float p = valid ? __expf(th) : 0.f;
            lsum[j] += p;
            Ps[(wid * 16 + lq * 4 + j) * PP + nt * 16 + lr] = (bf16_t)p;
          }
        }
      }

      __builtin_amdgcn_s_setprio(1);
#pragma unroll
      for (int ks = 0; ks < 2; ++ks) {
        bf16x8 pf = *(const bf16x8*)&Ps[(wid * 16 + lr) * PP + ks * 32 + lk];
#pragma unroll
        for (int nt = 0; nt < 16; ++nt) {
          const int R = nt * 16 + lr;
          bf16x8 vf = *(const bf16x8*)((const char*)Vc + R * 128 +
                                       (((ks * 4 + hi) ^ (R & 7)) << 4));
          o[nt] = __builtin_amdgcn_mfma_f32_16x16x32_bf16(pf, vf, o[nt], 0, 0, 0);
        }
      }
      __builtin_amdgcn_s_setprio(0);
    }

    __syncthreads();
  }

#pragma unroll
  for (int j = 0; j < 4; ++j) {
    float l = lsum[j];
    l += __shfl_xor(l, 1);
    l += __shfl_xor(l, 2);
    l += __shfl_xor(l, 4);
    l += __shfl_xor(l, 8);
    const float inv = 1.f / l;
    const int t_ = trw + lq * 4 + j;
    bf16_t* op = AV + ((size_t)(b * SS + t_)) * (SNQ * SH) + head * SH;
#pragma unroll
    for (int nt = 0; nt < 16; ++nt) op[nt * 16 + lr] = (bf16_t)(o[nt][j] * inv);
  }
}

// ------------------------------------------------------------------- host
extern "C" void kernel_launch(void* const* d_in, const int* in_sizes, int n_in,
                              void* d_out, int out_size, void* d_ws, size_t ws_size,
                              hipStream_t stream) {
  const float* x = (const float*)d_in[0];
  const float* Wq = (const float*)d_in[1];
  const float* Wk = (const float*)d_in[2];
  const float* Wv = (const float*)d_in[3];
  const float* Wo = (const float*)d_in[4];
  float* out = (float*)d_out;

  char* ws = (char*)d_ws;
  size_t off = 0;
  auto alloc = [&](size_t elems) {
    bf16_t* p = (bf16_t*)(ws + off);
    off += ((elems * 2 + 255) & ~(size_t)255);
    return p;
  };
  const size_t MS = (size_t)SB * SS;        // 4096 rows
  bf16_t* xb     = alloc(MS * SD);                 // [4096][2048]
  bf16_t* wqkvT  = alloc((size_t)QKVP * SD);       // [8192][2048]: Wq|Wk|Wv
  bf16_t* woT    = alloc((size_t)SD * SNQ * SH);   // [2048][4096]
  bf16_t* qkv    = alloc(MS * QKVP);               // [4096][8192]: Q|·|·
  bf16_t* kb     = alloc(MS * SNKV * SH);          // [B][NKV][S][H] (roped)
  bf16_t* vt     = alloc(MS * SNKV * SH);          // [B][NKV][H][S]
  bf16_t* av     = alloc(MS * SNQ * SH);           // [4096][4096]
  (void)ws_size;  // ~178 MB

  prep_kernel<<<14336, 256, 0, stream>>>(x, Wq, Wk, Wv, Wo, xb, wqkvT, woT);

  // fused Q|K|V projection; K roped -> kb, V transposed -> vt (epilogues)
  gemm8p<256, 1><<<512, 512, 0, stream>>>(xb, wqkvT, qkv, kb, vt, 4096, QKVP, 2048);

  attn_kernel<<<512, 512, 0, stream>>>(qkv, kb, vt, av);

  // O-proj: [4096x4096] x [2048x4096]^T -> [4096][2048] f32, 256 blocks
  gemm8p<128, 2><<<256, 512, 0, stream>>>(av, woT, out, nullptr, nullptr, 4096, 2048, 4096);
}